// Round 3
// baseline (371.347 us; speedup 1.0000x reference)
//
#include <hip/hip_runtime.h>

// HyperConv: y[b,o,t] = sum_{i<3} sum_{c<16} x[b,c,t+8-4i] * w_b[i*16+c][o]
// w_b = LeakyReLU(p[b]@W1 + b1) @ W2 + b2, reshaped [48][16].
//
// R1: 84 VGPR -> 4 waves/SIMD (gfx950 waves halve at vgpr={64,128,256}),
//     latency-bound at 87us (VALU 29%, HBM 29%).
// R2: 160 VGPR -> 2 waves/SIMD, 145us. Occupancy is the lever.
// R3: split outputs across threads: each thread does 4t x 8o (acc=32 VGPR),
//     two o-halves per block share x via L1. __launch_bounds__(256,8)
//     forces <=64 VGPR -> 8 waves/SIMD. w from LDS (wave-uniform broadcast).

#define NB 32
#define IN_CH 16
#define OUT_CH 16
#define KW 3
#define COND 8
#define T_OUT 65536
#define PADT 8
#define XT (T_OUT + PADT)            // 65544, float4-aligned rows
#define W2COLS (IN_CH * OUT_CH * KW) // 768
#define TPB 256
#define TPT 4                        // t per thread
#define O_PER_THREAD 8
#define TS_PER_BLOCK 128             // t-threads per block
#define T_PER_BLOCK (TS_PER_BLOCK * TPT)      // 512
#define BLOCKS_PER_B (T_OUT / T_PER_BLOCK)    // 128

__global__ __launch_bounds__(TPB, 8)
void hyperconv_kernel(const float* __restrict__ x,
                      const float* __restrict__ p,
                      const float* __restrict__ W1,
                      const float* __restrict__ b1,
                      const float* __restrict__ W2,
                      const float* __restrict__ b2,
                      float* __restrict__ y)
{
    __shared__ float h_lds[IN_CH];
    __shared__ float w_lds[W2COLS];  // [row=i*16+c][o]

    const int tid   = threadIdx.x;
    const int b     = blockIdx.x >> 7;        // / BLOCKS_PER_B
    const int chunk = blockIdx.x & (BLOCKS_PER_B - 1);

    // ---- hypernetwork: h = LeakyReLU(p[b] @ W1 + b1) ----
    if (tid < IN_CH) {
        float acc = b1[tid];
#pragma unroll
        for (int j = 0; j < COND; ++j)
            acc += p[b * COND + j] * W1[j * IN_CH + tid];
        h_lds[tid] = acc > 0.f ? acc : 0.2f * acc;
    }
    __syncthreads();

    // ---- w = h @ W2 + b2 : 768 entries, 3 per thread ----
#pragma unroll
    for (int r = 0; r < 3; ++r) {
        const int n = tid * 3 + r;
        float acc = b2[n];
#pragma unroll
        for (int c = 0; c < IN_CH; ++c)
            acc += h_lds[c] * W2[c * W2COLS + n];
        w_lds[n] = acc;
    }
    __syncthreads();

    // ---- main conv: 4 consecutive t x 8 outputs per thread ----
    const int ohalf = tid >> 7;               // 0 or 1
    const int ts    = tid & (TS_PER_BLOCK - 1);
    const int t0    = chunk * T_PER_BLOCK + ts * TPT;
    const float* xb = x + (size_t)b * IN_CH * XT + t0;
    const float* wbase = w_lds + ohalf * O_PER_THREAD;

    float4 acc[O_PER_THREAD];
#pragma unroll
    for (int o = 0; o < O_PER_THREAD; ++o) acc[o] = make_float4(0.f, 0.f, 0.f, 0.f);

#pragma unroll 4
    for (int c = 0; c < IN_CH; ++c) {
        const float* q = xb + c * XT;
        const float4 a0 = *(const float4*)(q);      // x[t+0..3]  -> tap i=2
        const float4 a1 = *(const float4*)(q + 4);  // x[t+4..7]  -> tap i=1
        const float4 a2 = *(const float4*)(q + 8);  // x[t+8..11] -> tap i=0
#pragma unroll
        for (int k = 0; k < KW; ++k) {
            const int i = 2 - k;                    // tap index
            const float4 v = (k == 0) ? a0 : (k == 1) ? a1 : a2;
            const float* wr = wbase + (i * IN_CH + c) * OUT_CH;
            const float4 w0 = *(const float4*)(wr);      // o+0..3
            const float4 w1 = *(const float4*)(wr + 4);  // o+4..7
            acc[0].x += v.x * w0.x; acc[0].y += v.y * w0.x;
            acc[0].z += v.z * w0.x; acc[0].w += v.w * w0.x;
            acc[1].x += v.x * w0.y; acc[1].y += v.y * w0.y;
            acc[1].z += v.z * w0.y; acc[1].w += v.w * w0.y;
            acc[2].x += v.x * w0.z; acc[2].y += v.y * w0.z;
            acc[2].z += v.z * w0.z; acc[2].w += v.w * w0.z;
            acc[3].x += v.x * w0.w; acc[3].y += v.y * w0.w;
            acc[3].z += v.z * w0.w; acc[3].w += v.w * w0.w;
            acc[4].x += v.x * w1.x; acc[4].y += v.y * w1.x;
            acc[4].z += v.z * w1.x; acc[4].w += v.w * w1.x;
            acc[5].x += v.x * w1.y; acc[5].y += v.y * w1.y;
            acc[5].z += v.z * w1.y; acc[5].w += v.w * w1.y;
            acc[6].x += v.x * w1.z; acc[6].y += v.y * w1.z;
            acc[6].z += v.z * w1.z; acc[6].w += v.w * w1.z;
            acc[7].x += v.x * w1.w; acc[7].y += v.y * w1.w;
            acc[7].z += v.z * w1.w; acc[7].w += v.w * w1.w;
        }
    }

    float* yb = y + (size_t)b * OUT_CH * T_OUT + (size_t)(ohalf * O_PER_THREAD) * T_OUT + t0;
#pragma unroll
    for (int o = 0; o < O_PER_THREAD; ++o)
        *(float4*)(yb + o * T_OUT) = acc[o];
}

extern "C" void kernel_launch(void* const* d_in, const int* in_sizes, int n_in,
                              void* d_out, int out_size, void* d_ws, size_t ws_size,
                              hipStream_t stream) {
    const float* x  = (const float*)d_in[0];
    const float* p  = (const float*)d_in[1];
    const float* W1 = (const float*)d_in[2];
    const float* b1 = (const float*)d_in[3];
    const float* W2 = (const float*)d_in[4];
    const float* b2 = (const float*)d_in[5];
    float* y = (float*)d_out;

    dim3 grid(NB * BLOCKS_PER_B);   // 4096 blocks
    dim3 block(TPB);
    hyperconv_kernel<<<grid, block, 0, stream>>>(x, p, W1, b1, W2, b2, y);
}